// Round 10
// baseline (243.310 us; speedup 1.0000x reference)
//
#include <hip/hip_runtime.h>
#include <stdint.h>

typedef __bf16 bf16;
typedef __bf16 bf16x4 __attribute__((ext_vector_type(4)));
typedef __bf16 bf16x8 __attribute__((ext_vector_type(8)));
typedef float f32x4 __attribute__((ext_vector_type(4)));
typedef float f32x16 __attribute__((ext_vector_type(16)));
typedef unsigned int uintx2 __attribute__((ext_vector_type(2)));
typedef unsigned int uintx4 __attribute__((ext_vector_type(4)));

#define MFMA16(a, b, c) __builtin_amdgcn_mfma_f32_16x16x32_bf16((a), (b), (c), 0, 0, 0)
#define MFMA32(a, b, c) __builtin_amdgcn_mfma_f32_32x32x16_bf16((a), (b), (c), 0, 0, 0)

// Async global->LDS, 16 B per lane: lane i's 16 B lands at ldsbase + i*16
// (wave-uniform base, m104/m108). Global address is per-lane.
__device__ __forceinline__ void gload16(const bf16* g, bf16* l) {
    __builtin_amdgcn_global_load_lds(
        (const __attribute__((address_space(1))) void*)g,
        (__attribute__((address_space(3))) void*)l, 16, 0, 0);
}

__device__ __forceinline__ float fast_exp2(float x) {
#if __has_builtin(__builtin_amdgcn_exp2f)
    return __builtin_amdgcn_exp2f(x);
#else
    return exp2f(x);
#endif
}

// ---------------------------------------------------------------------------
// prep: Wo fp32->bf16 (blocks 0..511) + mask pack (blocks 512..1535).
// ---------------------------------------------------------------------------
__global__ __launch_bounds__(256) void prep_kernel(
    const float* __restrict__ wo, const int* __restrict__ mask,
    bf16* __restrict__ wob, unsigned long long* __restrict__ maskb)
{
    int bid = blockIdx.x;
    if (bid < 512) {
        int i = (bid * 256 + threadIdx.x) * 8;
        float4 f0 = *(const float4*)(wo + i);
        float4 f1 = *(const float4*)(wo + i + 4);
        bf16x8 o;
        o[0] = (bf16)f0.x; o[1] = (bf16)f0.y; o[2] = (bf16)f0.z; o[3] = (bf16)f0.w;
        o[4] = (bf16)f1.x; o[5] = (bf16)f1.y; o[6] = (bf16)f1.z; o[7] = (bf16)f1.w;
        *(bf16x8*)(wob + i) = o;
        return;
    }
    int t16 = (bid - 512) * 256 + threadIdx.x;
    const int4* mp = (const int4*)mask + (size_t)t16 * 4;
    unsigned bits = 0;
#pragma unroll
    for (int c = 0; c < 4; ++c) {
        int4 a = mp[c];
        bits |= (unsigned)(a.x != 0) << (c * 4 + 0);
        bits |= (unsigned)(a.y != 0) << (c * 4 + 1);
        bits |= (unsigned)(a.z != 0) << (c * 4 + 2);
        bits |= (unsigned)(a.w != 0) << (c * 4 + 3);
    }
    unsigned long long u = (unsigned long long)bits << (16 * (threadIdx.x & 3));
    u |= __shfl_xor(u, 1, 64);
    u |= __shfl_xor(u, 2, 64);
    if ((threadIdx.x & 3) == 0) maskb[t16 >> 2] = u;
}

// ---------------------------------------------------------------------------
// QKV GEMM with FUSED fp32->bf16 conversion, v2 (R9 was latency-bound:
// MfmaUtil 13%, 77% idle -- one reg-set gave writebufs only ~1 compute phase
// of load cover, and __syncthreads' vmcnt(0) drained the lookahead loads).
// Fixes (both validated by R8's gemm_out which passed with this pattern):
//  * raw s_barrier + lgkmcnt(0) ONLY -- in-flight global loads cross the
//    barrier (LDS-write visibility needs lgkm, not vm).
//  * DOUBLE reg-set (R0 even tiles, R1 odd), loads issued 2 tiles ahead:
//    the implicit vmcnt before writebufs becomes a counted wait (older 8 of
//    16 outstanding) with ~2 compute phases of cover.
// Pipeline (1 barrier/step, ping-pong LDS bufs):
//   prologue: load(R0,0); load(R1,1); write(buf0,R0); load(R0,2)
//   step t:   lgkmcnt(0); s_barrier; write(buf[t+1], R[t+1]); load(R, t+3);
//             compute(buf[t])
// Hazards: buf X overwritten at step t only after the barrier ending all
// reads of X (compute(t-1)); R-set reloaded only after its tile was written.
// Conversion = same scalar bf16 cast as the old cvt kernel (bits identical).
// XCD remap; z==0 folds log2(e)/32 into Q; z==2 writes key-permuted Vt.
// ---------------------------------------------------------------------------
__global__ __launch_bounds__(256) void gemm_qkv_kernel(
    const float* __restrict__ A0, const float* __restrict__ A1, const float* __restrict__ A2,
    const float* __restrict__ B0, const float* __restrict__ B1, const float* __restrict__ B2,
    bf16* __restrict__ C0, bf16* __restrict__ C1, bf16* __restrict__ Vt)
{
    __shared__ bf16 smem[17408];     // 2 bufs x (A 4096 + B 4096) = 32 KB; V-epi 34 KB
    bf16* A0l = smem;
    bf16* B0l = smem + 4096;
    bf16* A1l = smem + 8192;
    bf16* B1l = smem + 12288;

    const int f = blockIdx.x + 8 * blockIdx.y + 256 * blockIdx.z;
    const int xcd = f & 7, sidx = f >> 3;
    const int z  = sidx >> 5;
    const int m0 = (xcd * 4 + (sidx & 3)) * 128;
    const int n0 = ((sidx >> 2) & 7) * 128;

    const float* A = (z == 0) ? A0 : (z == 1) ? A1 : A2;
    const float* B = (z == 0) ? B0 : (z == 1) ? B1 : B2;

    const int tid  = threadIdx.x;
    const int lane = tid & 63;
    const int wave = tid >> 6;
    const int quad = lane >> 4;
    const int l16  = lane & 15;
    const int wm = (wave >> 1) * 64;
    const int wn = (wave & 1) * 64;

    const int lrow = lane >> 2;          // 0..15
    const int lcol = (lane & 3) * 8;     // 0,8,16,24

    f32x4 acc[4][4] = {};
    float4 Ra[2][2][2], Rb[2][2][2];     // [set][chunk j][half]

    const float* Ag = A + (size_t)(m0 + wave * 32 + lrow) * 1024 + lcol;
    const float* Bg = B + (size_t)(n0 + wave * 32 + lrow) * 1024 + lcol;
    const int lds_off = lrow * 32 + lcol;

    auto loadregs = [&](int s, int t) {
        int k0 = t * 32;
#pragma unroll
        for (int j = 0; j < 2; ++j) {
            Ra[s][j][0] = *(const float4*)(Ag + (size_t)(j * 16) * 1024 + k0);
            Ra[s][j][1] = *(const float4*)(Ag + (size_t)(j * 16) * 1024 + k0 + 4);
            Rb[s][j][0] = *(const float4*)(Bg + (size_t)(j * 16) * 1024 + k0);
            Rb[s][j][1] = *(const float4*)(Bg + (size_t)(j * 16) * 1024 + k0 + 4);
        }
    };
    auto writebufs = [&](bf16* At, bf16* Bt, int s) {
#pragma unroll
        for (int j = 0; j < 2; ++j) {
            bf16x8 oa, ob;
            oa[0] = (bf16)Ra[s][j][0].x; oa[1] = (bf16)Ra[s][j][0].y;
            oa[2] = (bf16)Ra[s][j][0].z; oa[3] = (bf16)Ra[s][j][0].w;
            oa[4] = (bf16)Ra[s][j][1].x; oa[5] = (bf16)Ra[s][j][1].y;
            oa[6] = (bf16)Ra[s][j][1].z; oa[7] = (bf16)Ra[s][j][1].w;
            ob[0] = (bf16)Rb[s][j][0].x; ob[1] = (bf16)Rb[s][j][0].y;
            ob[2] = (bf16)Rb[s][j][0].z; ob[3] = (bf16)Rb[s][j][0].w;
            ob[4] = (bf16)Rb[s][j][1].x; ob[5] = (bf16)Rb[s][j][1].y;
            ob[6] = (bf16)Rb[s][j][1].z; ob[7] = (bf16)Rb[s][j][1].w;
            *(bf16x8*)(At + (wave * 32 + j * 16) * 32 + lds_off) = oa;
            *(bf16x8*)(Bt + (wave * 32 + j * 16) * 32 + lds_off) = ob;
        }
    };
    auto compute = [&](const bf16* At, const bf16* Bt) {
        bf16x8 af[4], bg[4];
#pragma unroll
        for (int i = 0; i < 4; ++i)
            af[i] = *(const bf16x8*)(At + (wm + i * 16 + l16) * 32 + quad * 8);
#pragma unroll
        for (int j = 0; j < 4; ++j)
            bg[j] = *(const bf16x8*)(Bt + (wn + j * 16 + l16) * 32 + quad * 8);
#pragma unroll
        for (int i = 0; i < 4; ++i)
#pragma unroll
            for (int j = 0; j < 4; ++j)
                acc[i][j] = MFMA16(af[i], bg[j], acc[i][j]);
    };

    loadregs(0, 0);                   // R0 <- tile 0
    loadregs(1, 1);                   // R1 <- tile 1
    writebufs(A0l, B0l, 0);           // buf0 <- tile 0 (waits R0: vmcnt(8))
    loadregs(0, 2);                   // R0 <- tile 2

    for (int t = 0; t < 32; t += 2) {
        // ---- step t: compute tile t from buf0 ----
        asm volatile("s_waitcnt lgkmcnt(0)" ::: "memory");   // publish ds_writes
        __builtin_amdgcn_s_barrier();
        __builtin_amdgcn_sched_barrier(0);
        writebufs(A1l, B1l, 1);                 // tile t+1 (waits R1 only)
        if (t + 3 < 32) loadregs(1, t + 3);     // R1 <- tile t+3
        compute(A0l, B0l);

        // ---- step t+1: compute tile t+1 from buf1 ----
        asm volatile("s_waitcnt lgkmcnt(0)" ::: "memory");
        __builtin_amdgcn_s_barrier();
        __builtin_amdgcn_sched_barrier(0);
        if (t + 2 < 32) {
            writebufs(A0l, B0l, 0);             // tile t+2 (waits R0 only)
            if (t + 4 < 32) loadregs(0, t + 4); // R0 <- tile t+4
        }
        compute(A1l, B1l);
    }

    if (z == 2) {
        // ---- fused V-transpose epilogue (aliases staging buffers) ----
        __syncthreads();                  // all frag reads of smem done
        const int qsw = ((quad & 1) << 1) | (quad >> 1);
#pragma unroll
        for (int i = 0; i < 4; ++i)
#pragma unroll
            for (int j = 0; j < 4; ++j) {
                int e  = wn + j * 16 + l16;
                int sp = wm + i * 16 + qsw * 4;
                bf16x4 v4;
#pragma unroll
                for (int r = 0; r < 4; ++r) v4[r] = (bf16)acc[i][j][r];
                *(bf16x4*)(smem + e * 136 + sp) = v4;
            }
        __syncthreads();
        const int bq = m0 >> 11;
        const int srow = m0 & 2047;
#pragma unroll
        for (int c = 0; c < 2; ++c) {
            int idx = c * 256 + tid;
            int e = idx >> 2, sc = (idx & 3) * 32;
            bf16* dst = Vt + (size_t)(bq * 1024 + n0 + e) * 2048 + srow + sc;
#pragma unroll
            for (int kk = 0; kk < 4; ++kk)
                *(bf16x8*)(dst + kk * 8) =
                    *(const bf16x8*)(smem + e * 136 + sc + kk * 8);
        }
        return;
    }
    bf16* C = (z == 0) ? C0 : C1;
    // z==0 (Q): (1/sqrt(1024)) * log2(e) so flash's exp2 == exp.
    const float cs = (z == 0) ? 0.0450842200277800f : 1.0f;
#pragma unroll
    for (int i = 0; i < 4; ++i)
#pragma unroll
        for (int j = 0; j < 4; ++j) {
            int row = m0 + wm + i * 16 + quad * 4;
            int col = n0 + wn + j * 16 + l16;
#pragma unroll
            for (int r = 0; r < 4; ++r)
                C[(row + r) * 1024 + col] = (bf16)(acc[i][j][r] * cs);
        }
}

// ---------------------------------------------------------------------------
// Out-projection GEMM (bf16 in), 128x64 tile, 3-buffer counted-vmcnt pipeline
// (unchanged from R8, passed): steady step s_waitcnt vmcnt(3) -> s_barrier ->
// stage(t+2) -> compute(t); last two steps vmcnt(3)/vmcnt(0). 512 blocks.
// ---------------------------------------------------------------------------
__global__ __launch_bounds__(256) void gemm_out_kernel(
    const bf16* __restrict__ Ab, const bf16* __restrict__ Bb,
    const float* __restrict__ bias, float* __restrict__ outf)
{
    constexpr int BUFSZ = 4096 + 2048;
    __shared__ bf16 smem[3 * BUFSZ];

    const int f = blockIdx.x + 8 * blockIdx.y;
    const int xcd = f & 7, sidx = f >> 3;
    const int m0 = (xcd * 4 + (sidx & 3)) * 128;
    const int n0 = (sidx >> 2) * 64;

    const int tid  = threadIdx.x;
    const int lane = tid & 63;
    const int wave = tid >> 6;
    const int quad = lane >> 4;
    const int l16  = lane & 15;
    const int wm = (wave >> 1) * 64;
    const int wn = (wave & 1) * 32;

    const int lrow = lane >> 2;
    const int lcol = (lane & 3) * 8;

    f32x4 acc[4][2] = {};

    const bf16* Ag = Ab + (size_t)(m0 + lrow) * 1024 + lcol;
    const bf16* Bg = Bb + (size_t)(n0 + lrow) * 1024 + lcol;

    bf16* buf0 = smem;
    bf16* buf1 = smem + BUFSZ;
    bf16* buf2 = smem + 2 * BUFSZ;

    auto stage = [&](bf16* base, int k0) {
#pragma unroll
        for (int j = 0; j < 2; ++j)
            gload16(Ag + (size_t)(wave * 32 + j * 16) * 1024 + k0,
                    base + (wave * 32 + j * 16) * 32);
        gload16(Bg + (size_t)(wave * 16) * 1024 + k0, base + 4096 + (wave * 16) * 32);
    };

    auto step = [&](bf16* cb, bf16* sb, int k0) {
        if (k0 == 992) {
            asm volatile("s_waitcnt vmcnt(0)" ::: "memory");
        } else {
            asm volatile("s_waitcnt vmcnt(3)" ::: "memory");
        }
        __builtin_amdgcn_s_barrier();
        __builtin_amdgcn_sched_barrier(0);
        if (k0 + 64 < 1024) stage(sb, k0 + 64);

        const bf16* Btb = cb + 4096;
        bf16x8 af[4], bg[2];
#pragma unroll
        for (int i = 0; i < 4; ++i)
            af[i] = *(const bf16x8*)(cb + (wm + i * 16 + l16) * 32 + quad * 8);
#pragma unroll
        for (int j = 0; j < 2; ++j)
            bg[j] = *(const bf16x8*)(Btb + (wn + j * 16 + l16) * 32 + quad * 8);
#pragma unroll
        for (int i = 0; i < 4; ++i)
#pragma unroll
            for (int j = 0; j < 2; ++j)
                acc[i][j] = MFMA16(af[i], bg[j], acc[i][j]);
    };

    stage(buf0, 0);
    stage(buf1, 32);
    for (int k0 = 0; k0 < 960; k0 += 96) {
        step(buf0, buf2, k0);
        step(buf1, buf0, k0 + 32);
        step(buf2, buf1, k0 + 64);
    }
    step(buf0, buf2, 960);
    step(buf1, buf0, 992);

#pragma unroll
    for (int j = 0; j < 2; ++j) {
        int col = n0 + wn + j * 16 + l16;
        float bj = bias[col];
#pragma unroll
        for (int i = 0; i < 4; ++i) {
            int row = m0 + wm + i * 16 + quad * 4;
#pragma unroll
            for (int r = 0; r < 4; ++r)
                outf[(row + r) * 1024 + col] = acc[i][j][r] + bj;
        }
    }
}

// ---------------------------------------------------------------------------
// Flash attention v13 (FROZEN since r6, measured 57.4 us):
//  * 8-wave (512-thread) split-K blocks; partials combined through LDS.
//  * XCD remap: all 16 q-tile blocks of one (b,h) on ONE XCD (K/V L2-resident).
//  * Flag-free masking (sign-broadcast AND), permuted-Vt (no P exchange),
//    exp2 with prescaled Q, double-buffered K/V, one barrier per kt, setprio.
// 32x32 layouts (m74/m101): C/D col=lane&31, row=(reg&3)+8*(reg>>2)+4*(lane>>5);
// A[m=lane&31][k=(lane>>5)*8+j]; B[k=(lane>>5)*8+j][n=lane&31].
// ---------------------------------------------------------------------------
__global__ __launch_bounds__(512, 4) void flash_kernel(
    const bf16* __restrict__ Q, const bf16* __restrict__ K, const bf16* __restrict__ Vt,
    const unsigned long long* __restrict__ maskb, bf16* __restrict__ O)
{
    __shared__ char smem[65536];     // [half][K0|K1|V0|V1] 4x8KB each; combine alias

    const int tid  = threadIdx.x;
    const int lane = tid & 63;
    const int wave = tid >> 6;       // 0..7
    const int half = wave >> 2;      // key half 0/1
    const int w4   = wave & 3;       // q-subtile 0..3
    const int l32  = lane & 31;
    const int hl   = lane >> 5;      // 0/1
    const int l7   = lane & 7;

    // XCD-aware remap: flat -> (xcd, bh_local, qtile)
    const int flat = blockIdx.x + 16 * (blockIdx.y + 16 * blockIdx.z);
    const int xcd  = flat & 7;
    const int slot = flat >> 3;          // 0..63
    const int bh   = xcd * 4 + (slot >> 4);
    const int h  = bh & 15;
    const int b  = bh >> 4;
    const int q0 = (slot & 15) * 128;
    const int qt = q0 + w4 * 32;     // wave's q rows qt..qt+31

    bf16* hbase = (bf16*)smem + half * 16384;
    bf16* K0 = hbase;
    bf16* K1 = hbase + 4096;
    bf16* V0 = hbase + 8192;
    bf16* V1 = hbase + 12288;

    // Q B-frags: B[k=d(hl*8+j)][n=q(l32)], 4 k-steps of 16
    const bf16* Qb = Q + (size_t)(b * 2048 + qt + l32) * 1024 + h * 64 + hl * 8;
    bf16x8 qf[4];
#pragma unroll
    for (int ks = 0; ks < 4; ++ks) qf[ks] = *(const bf16x8*)(Qb + ks * 16);

    bf16x8 ones;
#pragma unroll
    for (int j = 0; j < 8; ++j) ones[j] = (bf16)1.0f;

    f32x16 acc[2] = {};
    f32x16 lacc = {};

    // DMA staging: each wave stages K rows w4*16..+15 and V rows w4*16..+15 of
    // its half's tile, 2 calls each (8 rows/call). Lane i -> local row i>>3,
    // LDS chunk i&7, global chunk (i&7)^(i>>3).
    const int dmarow = lane >> 3;
    const int dmacol = (l7 ^ dmarow) * 8;
    const bf16* Kg = K + (size_t)(b * 2048 + w4 * 16 + dmarow) * 1024 + h * 64 + dmacol;
    const bf16* Vg = Vt + (size_t)((b * 16 + h) * 64 + w4 * 16 + dmarow) * 2048 + dmacol;
    const unsigned long long* Mg = maskb + (size_t)(qt + l32) * 32 + half * 16;
    const int kbase = half * 1024;

    auto stage = [&](bf16* Kd, bf16* Vd, int ktAbs) {
        gload16(Kg + (size_t)ktAbs * 1024,       Kd + (w4 * 16) * 64);
        gload16(Kg + (size_t)(ktAbs + 8) * 1024, Kd + (w4 * 16 + 8) * 64);
        gload16(Vg + ktAbs,                      Vd + (w4 * 16) * 64);
        gload16(Vg + ktAbs + 8 * 2048,           Vd + (w4 * 16 + 8) * 64);
    };

    unsigned long long mw = Mg[0];
    stage(K0, V0, kbase);            // prologue: buf 0 <- first tile of half

    auto body = [&](const bf16* Kc, const bf16* Vc, bf16* Kn, bf16* Vn, int it) {
        __syncthreads();             // drains buf[cur] DMA; prev frag reads done
        unsigned long long mw_next = 0;
        if (it + 1 < 16) {           // uniform branch
            stage(Kn, Vn, kbase + (it + 1) * 64);   // overlaps compute below
            mw_next = Mg[it + 1];
        }

        // S^T = K Q^T: two 32-key tiles, C[m=key][n=q], then mask+exp2;
        // pa frags are direct bit_casts (permuted-Vt matches slot order).
        bf16x8 pa[4];
#pragma unroll
        for (int t = 0; t < 2; ++t) {
            f32x16 s = {};
            __builtin_amdgcn_s_setprio(1);
#pragma unroll
            for (int ks = 0; ks < 4; ++ks) {
                bf16x8 ka = *(const bf16x8*)(Kc + (t * 32 + l32) * 64 +
                                             (((ks * 2 + hl) ^ l7) * 8));
                s = MFMA32(ka, qf[ks], s);
            }
            __builtin_amdgcn_s_setprio(0);
            // reg g*4+r -> key t*32 + 4*hl + 8*g + r
            unsigned mwt = (unsigned)(mw >> (t * 32 + 4 * hl));
            unsigned W[4][2];
#pragma unroll
            for (int g = 0; g < 4; ++g) {
                bf16x4 pv;
#pragma unroll
                for (int r = 0; r < 4; ++r) {
                    float ev = fast_exp2(s[g * 4 + r]);   // Q pre-scaled log2e/32
                    // flag-free mask: broadcast bit (8g+r) to all 32 bits, AND.
                    unsigned msk = (unsigned)((int)(mwt << (31 - (8 * g + r))) >> 31);
                    unsigned evu = __builtin_bit_cast(unsigned, ev) & msk;
                    pv[r] = (bf16)__builtin_bit_cast(float, evu);
                }
                uintx2 u = __builtin_bit_cast(uintx2, pv);
                W[g][0] = u[0];
                W[g][1] = u[1];
            }
#pragma unroll
            for (int kh = 0; kh < 2; ++kh) {
                uintx4 aw = { W[2 * kh][0], W[2 * kh][1],
                              W[2 * kh + 1][0], W[2 * kh + 1][1] };
                pa[t * 2 + kh] = __builtin_bit_cast(bf16x8, aw);
            }
        }

        // PV: A=P (in-register), B=V[key-permuted][d] from swizzled Vl
        __builtin_amdgcn_s_setprio(1);
#pragma unroll
        for (int dt = 0; dt < 2; ++dt)
#pragma unroll
            for (int ks = 0; ks < 4; ++ks) {
                bf16x8 vb = *(const bf16x8*)(Vc + (dt * 32 + l32) * 64 +
                                             (((ks * 2 + hl) ^ l7) * 8));
                acc[dt] = MFMA32(pa[ks], vb, acc[dt]);
            }
#pragma unroll
        for (int ks = 0; ks < 4; ++ks)
            lacc = MFMA32(pa[ks], ones, lacc);   // row-sums, all n identical
        __builtin_amdgcn_s_setprio(0);

        mw = mw_next;
    };

    for (int it = 0; it < 16; it += 2) {
        body(K0, V0, K1, V1, it);
        body(K1, V1, K0, V0, it + 1);
    }

    // ---- combine halves through LDS (aliased over K/V buffers) ----
    __syncthreads();                 // all compute done; smem reusable
    float* cb = (float*)smem;        // 12 quads x 256 lanes x 16 B = 48 KB
    float* ex = cb + (w4 * 64 + lane) * 4;   // coalesced: lanes contiguous
    if (half == 1) {
#pragma unroll
        for (int i = 0; i < 4; ++i) {
            f32x4 t0, t1, t2;
#pragma unroll
            for (int j = 0; j < 4; ++j) {
                t0[j] = acc[0][i * 4 + j];
                t1[j] = acc[1][i * 4 + j];
                t2[j] = lacc[i * 4 + j];
            }
            *(f32x4*)(ex + (i + 0) * 1024) = t0;
            *(f32x4*)(ex + (i + 4) * 1024) = t1;
            *(f32x4*)(ex + (i + 8) * 1024) = t2;
        }
    }
    __syncthreads();
    if (half == 0) {
#pragma unroll
        for (int i = 0; i < 4; ++i) {
            f32x4 t0 = *(const f32x4*)(ex + (i + 0) * 1024);
            f32x4 t1 = *(const f32x4*)(ex + (i + 4) * 1024);
            f32x4 t2 = *(const f32x4*)(ex + (i + 8) * 1024);
#pragma unroll
            for (int j = 0; j < 4; ++j) {
                acc[0][i * 4 + j] += t0[j];
                acc[1][i * 4 + j] += t1[j];
                lacc[i * 4 + j]   += t2[j];
            }
        }

        // Epilogue: row q_rel = 4*hl + 8*g + r, col d = dt*32 + l32
        const size_t obase = (size_t)(b * 2048 + qt) * 1024 + h * 64;
#pragma unroll
        for (int g = 0; g < 4; ++g)
#pragma unroll
            for (int r = 0; r < 4; ++r) {
                int qr = 4 * hl + 8 * g + r;
                float inv = 1.0f / lacc[g * 4 + r];
                O[obase + (size_t)qr * 1024 + l32]      = (bf16)(acc[0][g * 4 + r] * inv);
                O[obase + (size_t)qr * 1024 + 32 + l32] = (bf16)(acc[1][g * 4 + r] * inv);
            }
    }
}

// ---------------------------------------------------------------------------
extern "C" void kernel_launch(void* const* d_in, const int* in_sizes, int n_in,
                              void* d_out, int out_size, void* d_ws, size_t ws_size,
                              hipStream_t stream)
{
    const float* q  = (const float*)d_in[0];
    const float* k  = (const float*)d_in[1];
    const float* v  = (const float*)d_in[2];
    const int* mask = (const int*)d_in[3];
    const float* wq = (const float*)d_in[4];
    const float* wk = (const float*)d_in[5];
    const float* wv = (const float*)d_in[6];
    const float* wo = (const float*)d_in[7];
    const float* bo = (const float*)d_in[8];
    float* out = (float*)d_out;

    char* p = (char*)d_ws;
    auto alloc = [&](size_t bytes) {
        char* r = p;
        p += (bytes + 255) & ~(size_t)255;
        return r;
    };
    const size_t SB = (size_t)4096 * 1024 * 2;
    const size_t WB = (size_t)1024 * 1024 * 2;
    bf16* wob = (bf16*)alloc(WB);
    bf16* Qp  = (bf16*)alloc(SB);
    bf16* Kp  = (bf16*)alloc(SB);
    bf16* Vtp = (bf16*)alloc(SB);
    bf16* Ob  = (bf16*)alloc(SB);
    unsigned long long* maskb = (unsigned long long*)alloc(2048 * 32 * 8);

    prep_kernel<<<dim3(1536), 256, 0, stream>>>(wo, mask, wob, maskb);

    gemm_qkv_kernel<<<dim3(8, 32, 3), 256, 0, stream>>>(
        q, k, v, wq, wk, wv, Qp, Kp, Vtp);

    flash_kernel<<<dim3(16, 16, 2), 512, 0, stream>>>(Qp, Kp, Vtp, maskb, Ob);

    gemm_out_kernel<<<dim3(8, 64, 1), 256, 0, stream>>>(Ob, wob, bo, out);
}

// Round 11
// 225.618 us; speedup vs baseline: 1.0784x; 1.0784x over previous
//
#include <hip/hip_runtime.h>
#include <stdint.h>

typedef __bf16 bf16;
typedef __bf16 bf16x4 __attribute__((ext_vector_type(4)));
typedef __bf16 bf16x8 __attribute__((ext_vector_type(8)));
typedef float f32x4 __attribute__((ext_vector_type(4)));
typedef float f32x16 __attribute__((ext_vector_type(16)));
typedef unsigned int uintx2 __attribute__((ext_vector_type(2)));
typedef unsigned int uintx4 __attribute__((ext_vector_type(4)));

#define MFMA16(a, b, c) __builtin_amdgcn_mfma_f32_16x16x32_bf16((a), (b), (c), 0, 0, 0)
#define MFMA32(a, b, c) __builtin_amdgcn_mfma_f32_32x32x16_bf16((a), (b), (c), 0, 0, 0)

// Async global->LDS, 16 B per lane: lane i's 16 B lands at ldsbase + i*16
// (wave-uniform base, m104/m108). Global address is per-lane.
__device__ __forceinline__ void gload16(const bf16* g, bf16* l) {
    __builtin_amdgcn_global_load_lds(
        (const __attribute__((address_space(1))) void*)g,
        (__attribute__((address_space(3))) void*)l, 16, 0, 0);
}

__device__ __forceinline__ float fast_exp2(float x) {
#if __has_builtin(__builtin_amdgcn_exp2f)
    return __builtin_amdgcn_exp2f(x);
#else
    return exp2f(x);
#endif
}

// ---------------------------------------------------------------------------
// fp32 -> bf16 for q,k,v (4M each) and Wq,Wk,Wv,Wo (1M each); z==7 packs the
// mask [2048][2048] int32 -> maskb [2048][32] uint64. (R8 version, verbatim —
// the fused-cvt experiment of R9/R10 was 2x slower: fp32 staging pays double
// L2 bytes + reg roundtrip and loses global_load_lds.)
// ---------------------------------------------------------------------------
__global__ __launch_bounds__(256) void cvt_kernel(
    const float* __restrict__ q, const float* __restrict__ k, const float* __restrict__ v,
    const float* __restrict__ wq, const float* __restrict__ wk,
    const float* __restrict__ wv, const float* __restrict__ wo,
    const int* __restrict__ mask,
    bf16* __restrict__ qb, bf16* __restrict__ kb, bf16* __restrict__ vb,
    bf16* __restrict__ wqb, bf16* __restrict__ wkb, bf16* __restrict__ wvb,
    bf16* __restrict__ wob, unsigned long long* __restrict__ maskb)
{
    int z = blockIdx.z;
    if (z == 7) {
        int t16 = blockIdx.x * 256 + threadIdx.x;   // one 16-elem chunk / thread
        if (t16 >= 262144) return;                  // 4M / 16
        const int4* mp = (const int4*)mask + (size_t)t16 * 4;
        unsigned bits = 0;
#pragma unroll
        for (int c = 0; c < 4; ++c) {
            int4 a = mp[c];
            bits |= (unsigned)(a.x != 0) << (c * 4 + 0);
            bits |= (unsigned)(a.y != 0) << (c * 4 + 1);
            bits |= (unsigned)(a.z != 0) << (c * 4 + 2);
            bits |= (unsigned)(a.w != 0) << (c * 4 + 3);
        }
        unsigned long long u = (unsigned long long)bits << (16 * (threadIdx.x & 3));
        u |= __shfl_xor(u, 1, 64);
        u |= __shfl_xor(u, 2, 64);
        if ((threadIdx.x & 3) == 0) maskb[t16 >> 2] = u;
        return;
    }
    const float* src; bf16* dst; int n;
    switch (z) {
        case 0:  src = q;  dst = qb;  n = 4194304; break;
        case 1:  src = k;  dst = kb;  n = 4194304; break;
        case 2:  src = v;  dst = vb;  n = 4194304; break;
        case 3:  src = wq; dst = wqb; n = 1048576; break;
        case 4:  src = wk; dst = wkb; n = 1048576; break;
        case 5:  src = wv; dst = wvb; n = 1048576; break;
        default: src = wo; dst = wob; n = 1048576; break;
    }
    int i = (blockIdx.x * 256 + threadIdx.x) * 8;
    if (i >= n) return;
    float4 f0 = *(const float4*)(src + i);
    float4 f1 = *(const float4*)(src + i + 4);
    bf16x8 o;
    o[0] = (bf16)f0.x; o[1] = (bf16)f0.y; o[2] = (bf16)f0.z; o[3] = (bf16)f0.w;
    o[4] = (bf16)f1.x; o[5] = (bf16)f1.y; o[6] = (bf16)f1.z; o[7] = (bf16)f1.w;
    *(bf16x8*)(dst + i) = o;
}

// ---------------------------------------------------------------------------
// QKV GEMM (bf16 in), 128x128 tile, 3-buffer counted-vmcnt pipeline (R8
// version, verbatim): steady step s_waitcnt vmcnt(4) -> s_barrier ->
// stage(t+2) -> compute(t); last two steps vmcnt(4)/vmcnt(0).
// XCD remap; z==0 (Q) folds (1/sqrt(1024))*log2(e); z==2 (V) writes
// key-permuted Vt via LDS (aliased over staging buffers).
// ---------------------------------------------------------------------------
__global__ __launch_bounds__(256) void gemm_qkv_kernel(
    const bf16* __restrict__ A0, const bf16* __restrict__ A1, const bf16* __restrict__ A2,
    const bf16* __restrict__ B0, const bf16* __restrict__ B1, const bf16* __restrict__ B2,
    bf16* __restrict__ C0, bf16* __restrict__ C1, bf16* __restrict__ Vt)
{
    constexpr int BUFSZ = 8192;              // A 4096 + B 4096 elems
    __shared__ bf16 smem[3 * BUFSZ];         // 48 KB; V-epi needs 34 KB (alias)

    const int f = blockIdx.x + 8 * blockIdx.y + 256 * blockIdx.z;
    const int xcd = f & 7, sidx = f >> 3;
    const int z  = sidx >> 5;
    const int m0 = (xcd * 4 + (sidx & 3)) * 128;
    const int n0 = ((sidx >> 2) & 7) * 128;

    const bf16* A = (z == 0) ? A0 : (z == 1) ? A1 : A2;
    const bf16* B = (z == 0) ? B0 : (z == 1) ? B1 : B2;

    const int tid  = threadIdx.x;
    const int lane = tid & 63;
    const int wave = tid >> 6;
    const int quad = lane >> 4;
    const int l16  = lane & 15;
    const int wm = (wave >> 1) * 64;
    const int wn = (wave & 1) * 64;

    const int lrow = lane >> 2;
    const int lcol = (lane & 3) * 8;

    f32x4 acc[4][4] = {};

    const bf16* Ag = A + (size_t)(m0 + lrow) * 1024 + lcol;
    const bf16* Bg = B + (size_t)(n0 + lrow) * 1024 + lcol;

    bf16* buf0 = smem;
    bf16* buf1 = smem + BUFSZ;
    bf16* buf2 = smem + 2 * BUFSZ;

    auto stage = [&](bf16* base, int k0) {
#pragma unroll
        for (int j = 0; j < 2; ++j)
            gload16(Ag + (size_t)(wave * 32 + j * 16) * 1024 + k0,
                    base + (wave * 32 + j * 16) * 32);
        bf16* Btb = base + 4096;
#pragma unroll
        for (int j = 0; j < 2; ++j)
            gload16(Bg + (size_t)(wave * 32 + j * 16) * 1024 + k0,
                    Btb + (wave * 32 + j * 16) * 32);
    };

    auto step = [&](bf16* cb, bf16* sb, int k0) {
        if (k0 == 992) {
            asm volatile("s_waitcnt vmcnt(0)" ::: "memory");
        } else {
            asm volatile("s_waitcnt vmcnt(4)" ::: "memory");
        }
        __builtin_amdgcn_s_barrier();
        __builtin_amdgcn_sched_barrier(0);
        if (k0 + 64 < 1024) stage(sb, k0 + 64);

        const bf16* Btb = cb + 4096;
        bf16x8 af[4], bg[4];
#pragma unroll
        for (int i = 0; i < 4; ++i)
            af[i] = *(const bf16x8*)(cb + (wm + i * 16 + l16) * 32 + quad * 8);
#pragma unroll
        for (int j = 0; j < 4; ++j)
            bg[j] = *(const bf16x8*)(Btb + (wn + j * 16 + l16) * 32 + quad * 8);
#pragma unroll
        for (int i = 0; i < 4; ++i)
#pragma unroll
            for (int j = 0; j < 4; ++j)
                acc[i][j] = MFMA16(af[i], bg[j], acc[i][j]);
    };

    stage(buf0, 0);
    stage(buf1, 32);
    for (int k0 = 0; k0 < 960; k0 += 96) {     // 10 triples = 30 steps
        step(buf0, buf2, k0);
        step(buf1, buf0, k0 + 32);
        step(buf2, buf1, k0 + 64);
    }
    step(buf0, buf2, 960);
    step(buf1, buf0, 992);

    if (z == 2) {
        // ---- fused V-transpose epilogue (aliases staging buffers) ----
        __syncthreads();                       // all frag reads done
        const int qsw = ((quad & 1) << 1) | (quad >> 1);
#pragma unroll
        for (int i = 0; i < 4; ++i)
#pragma unroll
            for (int j = 0; j < 4; ++j) {
                int e  = wn + j * 16 + l16;
                int sp = wm + i * 16 + qsw * 4;
                bf16x4 v4;
#pragma unroll
                for (int r = 0; r < 4; ++r) v4[r] = (bf16)acc[i][j][r];
                *(bf16x4*)(smem + e * 136 + sp) = v4;
            }
        __syncthreads();
        const int bq = m0 >> 11;
        const int srow = m0 & 2047;
#pragma unroll
        for (int c = 0; c < 2; ++c) {
            int idx = c * 256 + tid;
            int e = idx >> 2, sc = (idx & 3) * 32;
            bf16* dst = Vt + (size_t)(bq * 1024 + n0 + e) * 2048 + srow + sc;
#pragma unroll
            for (int kk = 0; kk < 4; ++kk)
                *(bf16x8*)(dst + kk * 8) =
                    *(const bf16x8*)(smem + e * 136 + sc + kk * 8);
        }
        return;
    }
    bf16* C = (z == 0) ? C0 : C1;
    // z==0 (Q): (1/sqrt(1024)) * log2(e) so flash's exp2 == exp.
    const float cs = (z == 0) ? 0.0450842200277800f : 1.0f;
#pragma unroll
    for (int i = 0; i < 4; ++i)
#pragma unroll
        for (int j = 0; j < 4; ++j) {
            int row = m0 + wm + i * 16 + quad * 4;
            int col = n0 + wn + j * 16 + l16;
#pragma unroll
            for (int r = 0; r < 4; ++r)
                C[(row + r) * 1024 + col] = (bf16)(acc[i][j][r] * cs);
        }
}

// ---------------------------------------------------------------------------
// Out-projection GEMM, SPLIT-K v2: 512 threads, waves 0-3 own K [0,512),
// waves 4-7 own K [512,1024). Each half runs the R8 3-buffer counted-vmcnt
// pipeline independently (16 steps instead of 32); block-wide s_barrier is
// legal because both halves execute identical step counts. 512 blocks x 8
// waves = 16 waves/CU (was 8 -- the same occupancy-starvation fix that took
// flash 76->57 in R3). LDS: 2 halves x 3 bufs x (A 8KB + B 4KB) = 72 KB ->
// 2 blocks/CU. Partial accs combined once through LDS; half 0 stores + bias.
// ---------------------------------------------------------------------------
__global__ __launch_bounds__(512) void gemm_out_kernel(
    const bf16* __restrict__ Ab, const bf16* __restrict__ Bb,
    const float* __restrict__ bias, float* __restrict__ outf)
{
    constexpr int BUFSZ = 4096 + 2048;       // A 128x32 + B 64x32 elems
    __shared__ bf16 smem[2 * 3 * BUFSZ];     // 72 KB

    const int f = blockIdx.x + 8 * blockIdx.y;   // 512 blocks
    const int xcd = f & 7, sidx = f >> 3;
    const int m0 = (xcd * 4 + (sidx & 3)) * 128;
    const int n0 = (sidx >> 2) * 64;

    const int tid  = threadIdx.x;
    const int lane = tid & 63;
    const int wave = tid >> 6;       // 0..7
    const int half = wave >> 2;      // K half
    const int w4   = wave & 3;
    const int quad = lane >> 4;
    const int l16  = lane & 15;
    const int wm = (w4 >> 1) * 64;
    const int wn = (w4 & 1) * 32;

    const int lrow = lane >> 2;
    const int lcol = (lane & 3) * 8;
    const int kbase = half * 512;

    f32x4 acc[4][2] = {};

    const bf16* Ag = Ab + (size_t)(m0 + lrow) * 1024 + lcol + kbase;
    const bf16* Bg = Bb + (size_t)(n0 + lrow) * 1024 + lcol + kbase;

    bf16* hb   = smem + half * 3 * BUFSZ;
    bf16* buf0 = hb;
    bf16* buf1 = hb + BUFSZ;
    bf16* buf2 = hb + 2 * BUFSZ;

    auto stage = [&](bf16* base, int k0) {   // k0 local to half: 0..511
#pragma unroll
        for (int j = 0; j < 2; ++j)
            gload16(Ag + (size_t)(w4 * 32 + j * 16) * 1024 + k0,
                    base + (w4 * 32 + j * 16) * 32);
        gload16(Bg + (size_t)(w4 * 16) * 1024 + k0, base + 4096 + (w4 * 16) * 32);
    };

    auto step = [&](bf16* cb, bf16* sb, int k0) {
        if (k0 == 480) {
            asm volatile("s_waitcnt vmcnt(0)" ::: "memory");
        } else {
            asm volatile("s_waitcnt vmcnt(3)" ::: "memory");
        }
        __builtin_amdgcn_s_barrier();
        __builtin_amdgcn_sched_barrier(0);
        if (k0 + 64 < 512) stage(sb, k0 + 64);

        const bf16* Btb = cb + 4096;
        bf16x8 af[4], bg[2];
#pragma unroll
        for (int i = 0; i < 4; ++i)
            af[i] = *(const bf16x8*)(cb + (wm + i * 16 + l16) * 32 + quad * 8);
#pragma unroll
        for (int j = 0; j < 2; ++j)
            bg[j] = *(const bf16x8*)(Btb + (wn + j * 16 + l16) * 32 + quad * 8);
#pragma unroll
        for (int i = 0; i < 4; ++i)
#pragma unroll
            for (int j = 0; j < 2; ++j)
                acc[i][j] = MFMA16(af[i], bg[j], acc[i][j]);
    };

    stage(buf0, 0);
    stage(buf1, 32);
    for (int k0 = 0; k0 < 480; k0 += 96) {   // 5 triples = 15 steps (k 0..448)
        step(buf0, buf2, k0);
        step(buf1, buf0, k0 + 32);
        step(buf2, buf1, k0 + 64);
    }
    step(buf0, buf1, 480);                   // 16th step; vmcnt(0), no stage

    // ---- combine halves through LDS (aliases staging buffers) ----
    __syncthreads();
    float* ex = (float*)smem + (w4 * 64 + lane) * 4;   // 8 slots x 1024 floats
    if (half == 1) {
#pragma unroll
        for (int i = 0; i < 4; ++i) {
            *(f32x4*)(ex + (i + 0) * 1024) = acc[i][0];
            *(f32x4*)(ex + (i + 4) * 1024) = acc[i][1];
        }
    }
    __syncthreads();
    if (half == 0) {
#pragma unroll
        for (int i = 0; i < 4; ++i) {
            f32x4 t0 = *(const f32x4*)(ex + (i + 0) * 1024);
            f32x4 t1 = *(const f32x4*)(ex + (i + 4) * 1024);
#pragma unroll
            for (int j = 0; j < 4; ++j) {
                acc[i][0][j] += t0[j];
                acc[i][1][j] += t1[j];
            }
        }
#pragma unroll
        for (int j = 0; j < 2; ++j) {
            int col = n0 + wn + j * 16 + l16;
            float bj = bias[col];
#pragma unroll
            for (int i = 0; i < 4; ++i) {
                int row = m0 + wm + i * 16 + quad * 4;
#pragma unroll
                for (int r = 0; r < 4; ++r)
                    outf[(row + r) * 1024 + col] = acc[i][j][r] + bj;
            }
        }
    }
}

// ---------------------------------------------------------------------------
// Flash attention v13 (FROZEN since r6, measured 57.4 us):
//  * 8-wave (512-thread) split-K blocks; partials combined through LDS.
//  * XCD remap: all 16 q-tile blocks of one (b,h) on ONE XCD (K/V L2-resident).
//  * Flag-free masking (sign-broadcast AND), permuted-Vt (no P exchange),
//    exp2 with prescaled Q, double-buffered K/V, one barrier per kt, setprio.
// 32x32 layouts (m74/m101): C/D col=lane&31, row=(reg&3)+8*(reg>>2)+4*(lane>>5);
// A[m=lane&31][k=(lane>>5)*8+j]; B[k=(lane>>5)*8+j][n=lane&31].
// ---------------------------------------------------------------------------
__global__ __launch_bounds__(512, 4) void flash_kernel(
    const bf16* __restrict__ Q, const bf16* __restrict__ K, const bf16* __restrict__ Vt,
    const unsigned long long* __restrict__ maskb, bf16* __restrict__ O)
{
    __shared__ char smem[65536];     // [half][K0|K1|V0|V1] 4x8KB each; combine alias

    const int tid  = threadIdx.x;
    const int lane = tid & 63;
    const int wave = tid >> 6;       // 0..7
    const int half = wave >> 2;      // key half 0/1
    const int w4   = wave & 3;       // q-subtile 0..3
    const int l32  = lane & 31;
    const int hl   = lane >> 5;      // 0/1
    const int l7   = lane & 7;

    // XCD-aware remap: flat -> (xcd, bh_local, qtile)
    const int flat = blockIdx.x + 16 * (blockIdx.y + 16 * blockIdx.z);
    const int xcd  = flat & 7;
    const int slot = flat >> 3;          // 0..63
    const int bh   = xcd * 4 + (slot >> 4);
    const int h  = bh & 15;
    const int b  = bh >> 4;
    const int q0 = (slot & 15) * 128;
    const int qt = q0 + w4 * 32;     // wave's q rows qt..qt+31

    bf16* hbase = (bf16*)smem + half * 16384;
    bf16* K0 = hbase;
    bf16* K1 = hbase + 4096;
    bf16* V0 = hbase + 8192;
    bf16* V1 = hbase + 12288;

    // Q B-frags: B[k=d(hl*8+j)][n=q(l32)], 4 k-steps of 16
    const bf16* Qb = Q + (size_t)(b * 2048 + qt + l32) * 1024 + h * 64 + hl * 8;
    bf16x8 qf[4];
#pragma unroll
    for (int ks = 0; ks < 4; ++ks) qf[ks] = *(const bf16x8*)(Qb + ks * 16);

    bf16x8 ones;
#pragma unroll
    for (int j = 0; j < 8; ++j) ones[j] = (bf16)1.0f;

    f32x16 acc[2] = {};
    f32x16 lacc = {};

    // DMA staging: each wave stages K rows w4*16..+15 and V rows w4*16..+15 of
    // its half's tile, 2 calls each (8 rows/call). Lane i -> local row i>>3,
    // LDS chunk i&7, global chunk (i&7)^(i>>3).
    const int dmarow = lane >> 3;
    const int dmacol = (l7 ^ dmarow) * 8;
    const bf16* Kg = K + (size_t)(b * 2048 + w4 * 16 + dmarow) * 1024 + h * 64 + dmacol;
    const bf16* Vg = Vt + (size_t)((b * 16 + h) * 64 + w4 * 16 + dmarow) * 2048 + dmacol;
    const unsigned long long* Mg = maskb + (size_t)(qt + l32) * 32 + half * 16;
    const int kbase = half * 1024;

    auto stage = [&](bf16* Kd, bf16* Vd, int ktAbs) {
        gload16(Kg + (size_t)ktAbs * 1024,       Kd + (w4 * 16) * 64);
        gload16(Kg + (size_t)(ktAbs + 8) * 1024, Kd + (w4 * 16 + 8) * 64);
        gload16(Vg + ktAbs,                      Vd + (w4 * 16) * 64);
        gload16(Vg + ktAbs + 8 * 2048,           Vd + (w4 * 16 + 8) * 64);
    };

    unsigned long long mw = Mg[0];
    stage(K0, V0, kbase);            // prologue: buf 0 <- first tile of half

    auto body = [&](const bf16* Kc, const bf16* Vc, bf16* Kn, bf16* Vn, int it) {
        __syncthreads();             // drains buf[cur] DMA; prev frag reads done
        unsigned long long mw_next = 0;
        if (it + 1 < 16) {           // uniform branch
            stage(Kn, Vn, kbase + (it + 1) * 64);   // overlaps compute below
            mw_next = Mg[it + 1];
        }

        // S^T = K Q^T: two 32-key tiles, C[m=key][n=q], then mask+exp2;
        // pa frags are direct bit_casts (permuted-Vt matches slot order).
        bf16x8 pa[4];
#pragma unroll
        for (int t = 0; t < 2; ++t) {
            f32x16 s = {};
            __builtin_amdgcn_s_setprio(1);
#pragma unroll
            for (int ks = 0; ks < 4; ++ks) {
                bf16x8 ka = *(const bf16x8*)(Kc + (t * 32 + l32) * 64 +
                                             (((ks * 2 + hl) ^ l7) * 8));
                s = MFMA32(ka, qf[ks], s);
            }
            __builtin_amdgcn_s_setprio(0);
            // reg g*4+r -> key t*32 + 4*hl + 8*g + r
            unsigned mwt = (unsigned)(mw >> (t * 32 + 4 * hl));
            unsigned W[4][2];
#pragma unroll
            for (int g = 0; g < 4; ++g) {
                bf16x4 pv;
#pragma unroll
                for (int r = 0; r < 4; ++r) {
                    float ev = fast_exp2(s[g * 4 + r]);   // Q pre-scaled log2e/32
                    // flag-free mask: broadcast bit (8g+r) to all 32 bits, AND.
                    unsigned msk = (unsigned)((int)(mwt << (31 - (8 * g + r))) >> 31);
                    unsigned evu = __builtin_bit_cast(unsigned, ev) & msk;
                    pv[r] = (bf16)__builtin_bit_cast(float, evu);
                }
                uintx2 u = __builtin_bit_cast(uintx2, pv);
                W[g][0] = u[0];
                W[g][1] = u[1];
            }
#pragma unroll
            for (int kh = 0; kh < 2; ++kh) {
                uintx4 aw = { W[2 * kh][0], W[2 * kh][1],
                              W[2 * kh + 1][0], W[2 * kh + 1][1] };
                pa[t * 2 + kh] = __builtin_bit_cast(bf16x8, aw);
            }
        }

        // PV: A=P (in-register), B=V[key-permuted][d] from swizzled Vl
        __builtin_amdgcn_s_setprio(1);
#pragma unroll
        for (int dt = 0; dt < 2; ++dt)
#pragma unroll
            for (int ks = 0; ks < 4; ++ks) {
                bf16x8 vb = *(const bf16x8*)(Vc + (dt * 32 + l32) * 64 +
                                             (((ks * 2 + hl) ^ l7) * 8));
                acc[dt] = MFMA32(pa[ks], vb, acc[dt]);
            }
#pragma unroll
        for (int ks = 0; ks < 4; ++ks)
            lacc = MFMA32(pa[ks], ones, lacc);   // row-sums, all n identical
        __builtin_amdgcn_s_setprio(0);

        mw = mw_next;
    };

    for (int it = 0; it < 16; it += 2) {
        body(K0, V0, K1, V1, it);
        body(K1, V1, K0, V0, it + 1);
    }

    // ---- combine halves through LDS (aliased over K/V buffers) ----
    __syncthreads();                 // all compute done; smem reusable
    float* cb = (float*)smem;        // 12 quads x 256 lanes x 16 B = 48 KB
    float* ex = cb + (w4 * 64 + lane) * 4;   // coalesced: lanes contiguous
    if (half == 1) {
#pragma unroll
        for (int i = 0; i < 4; ++i) {
            f32x4 t0, t1, t2;
#pragma unroll
            for (int j = 0; j < 4; ++j) {
                t0[j] = acc[0][i * 4 + j];
                t1[j] = acc[1][i * 4 + j];
                t2[j] = lacc[i * 4 + j];
            }
            *(f32x4*)(ex + (i + 0) * 1024) = t0;
            *(f32x4*)(ex + (i + 4) * 1024) = t1;
            *(f32x4*)(ex + (i + 8) * 1024) = t2;
        }
    }
    __syncthreads();
    if (half == 0) {
#pragma unroll
        for (int i = 0; i < 4; ++i) {
            f32x4 t0 = *(const f32x4*)(ex + (i + 0) * 1024);
            f32x4 t1 = *(const f32x4*)(ex + (i + 4) * 1024);
            f32x4 t2 = *(const f32x4*)(ex + (i + 8) * 1024);
#pragma unroll
            for (int j = 0; j < 4; ++j) {
                acc[0][i * 4 + j] += t0[j];
                acc[1][i * 4 + j] += t1[j];
                lacc[i * 4 + j]   += t2[j];
            }
        }

        // Epilogue: row q_rel = 4*hl + 8*g + r, col d = dt*32 + l32
        const size_t obase = (size_t)(b * 2048 + qt) * 1024 + h * 64;
#pragma unroll
        for (int g = 0; g < 4; ++g)
#pragma unroll
            for (int r = 0; r < 4; ++r) {
                int qr = 4 * hl + 8 * g + r;
                float inv = 1.0f / lacc[g * 4 + r];
                O[obase + (size_t)qr * 1024 + l32]      = (bf16)(acc[0][g * 4 + r] * inv);
                O[obase + (size_t)qr * 1024 + 32 + l32] = (bf16)(acc[1][g * 4 + r] * inv);
            }
    }
}

// ---------------------------------------------------------------------------
extern "C" void kernel_launch(void* const* d_in, const int* in_sizes, int n_in,
                              void* d_out, int out_size, void* d_ws, size_t ws_size,
                              hipStream_t stream)
{
    const float* q  = (const float*)d_in[0];
    const float* k  = (const float*)d_in[1];
    const float* v  = (const float*)d_in[2];
    const int* mask = (const int*)d_in[3];
    const float* wq = (const float*)d_in[4];
    const float* wk = (const float*)d_in[5];
    const float* wv = (const float*)d_in[6];
    const float* wo = (const float*)d_in[7];
    const float* bo = (const float*)d_in[8];
    float* out = (float*)d_out;

    char* p = (char*)d_ws;
    auto alloc = [&](size_t bytes) {
        char* r = p;
        p += (bytes + 255) & ~(size_t)255;
        return r;
    };
    const size_t SB = (size_t)4096 * 1024 * 2;
    const size_t WB = (size_t)1024 * 1024 * 2;
    bf16* qb  = (bf16*)alloc(SB);
    bf16* kb  = (bf16*)alloc(SB);
    bf16* vb  = (bf16*)alloc(SB);
    bf16* wqb = (bf16*)alloc(WB);
    bf16* wkb = (bf16*)alloc(WB);
    bf16* wvb = (bf16*)alloc(WB);
    bf16* wob = (bf16*)alloc(WB);
    bf16* Qp  = (bf16*)alloc(SB);
    bf16* Kp  = (bf16*)alloc(SB);
    bf16* Vtp = (bf16*)alloc(SB);
    bf16* Ob  = (bf16*)alloc(SB);
    unsigned long long* maskb = (unsigned long long*)alloc(2048 * 32 * 8);

    cvt_kernel<<<dim3(2048, 1, 8), 256, 0, stream>>>(
        q, k, v, wq, wk, wv, wo, mask, qb, kb, vb, wqb, wkb, wvb, wob, maskb);

    gemm_qkv_kernel<<<dim3(8, 32, 3), 256, 0, stream>>>(
        qb, kb, vb, wqb, wkb, wvb, Qp, Kp, Vtp);

    flash_kernel<<<dim3(16, 16, 2), 512, 0, stream>>>(Qp, Kp, Vtp, maskb, Ob);

    gemm_out_kernel<<<dim3(8, 64), 512, 0, stream>>>(Ob, wob, bo, out);
}